// Round 17
// baseline (195.469 us; speedup 1.0000x reference)
//
#include <hip/hip_runtime.h>
#include <hip/hip_bf16.h>

#define D_MODEL 1024
#define N_HEADS 16
#define D_HEAD  64
#define D_FF    2048
#define BATCH   4
#define SEQ     1024
#define ROWS    (BATCH*SEQ)   // 4096

typedef __bf16  bf16x8 __attribute__((ext_vector_type(8)));
typedef float   f32x4  __attribute__((ext_vector_type(4)));
typedef unsigned int u32x4 __attribute__((ext_vector_type(4)));
typedef unsigned int u32x2 __attribute__((ext_vector_type(2)));
typedef unsigned short u16;
typedef unsigned int u32;

__device__ inline u16 f2bf(float x){ __hip_bfloat16 b = __float2bfloat16(x); return *(u16*)&b; }
__device__ inline float b2f(u16 u){ u32 v = ((u32)u)<<16; return __builtin_bit_cast(float, v); }

#if __has_builtin(__builtin_amdgcn_exp2f)
__device__ inline float fexp2(float x){ return __builtin_amdgcn_exp2f(x); }
#else
__device__ inline float fexp2(float x){ return exp2f(x); }
#endif

// async global->LDS, 16B per lane. gsrc per-lane, ldst wave-uniform base (+lane*16 implicit).
__device__ inline void load_lds16(const u16* gsrc, u16* ldst){
  __builtin_amdgcn_global_load_lds((const __attribute__((address_space(1))) void*)gsrc,
                                   (__attribute__((address_space(3))) void*)ldst, 16, 0, 0);
}

// ---------------- prep: f32 -> bf16 cast ----------------
__global__ __launch_bounds__(256)
void cast_bf16_kernel(const float* __restrict__ src, __hip_bfloat16* __restrict__ dst, int n){
  int i = (blockIdx.x*blockDim.x + threadIdx.x)*4;
  if (i + 3 < n){
    float4 v = *(const float4*)(src + i);
    dst[i+0] = __float2bfloat16(v.x);
    dst[i+1] = __float2bfloat16(v.y);
    dst[i+2] = __float2bfloat16(v.z);
    dst[i+3] = __float2bfloat16(v.w);
  }
}

// 4 square 1024x1024 weights in one launch (z selects source; dst contiguous at z*1Mi)
__global__ __launch_bounds__(256)
void transpose4_kernel(const float* __restrict__ s0, const float* __restrict__ s1,
                       const float* __restrict__ s2, const float* __restrict__ s3,
                       __hip_bfloat16* __restrict__ dst){
  __shared__ float tile[32][33];
  const float* src = (blockIdx.z==0)?s0:(blockIdx.z==1)?s1:(blockIdx.z==2)?s2:s3;
  __hip_bfloat16* d = dst + (size_t)blockIdx.z*1024*1024;
  int c0 = blockIdx.x*32, r0 = blockIdx.y*32;
  int tx = threadIdx.x & 31, ty = threadIdx.x >> 5;
  #pragma unroll
  for (int i=0;i<32;i+=8)
    tile[ty+i][tx] = src[(size_t)(r0+ty+i)*1024 + (c0+tx)];
  __syncthreads();
  #pragma unroll
  for (int i=0;i<32;i+=8)
    d[(size_t)(c0+ty+i)*1024 + (r0+tx)] = __float2bfloat16(tile[tx][ty+i]);
}

// W1 (1024x2048) and W2 (2048x1024) transposed+cast in one launch (z selects)
__global__ __launch_bounds__(256)
void transpose_cast2_kernel(const float* __restrict__ W1, const float* __restrict__ W2,
                            __hip_bfloat16* __restrict__ W1T, __hip_bfloat16* __restrict__ W2T){
  __shared__ float tile[32][33];
  const float* src; __hip_bfloat16* dst; int R, C, c0, r0;
  if (blockIdx.z==0){ src=W1; dst=W1T; R=1024; C=2048; c0=blockIdx.x*32; r0=blockIdx.y*32; }
  else              { src=W2; dst=W2T; R=2048; C=1024; c0=blockIdx.y*32; r0=blockIdx.x*32; }
  int tx = threadIdx.x & 31, ty = threadIdx.x >> 5;
  #pragma unroll
  for (int i=0;i<32;i+=8)
    tile[ty+i][tx] = src[(size_t)(r0+ty+i)*C + (c0+tx)];
  __syncthreads();
  #pragma unroll
  for (int i=0;i<32;i+=8)
    dst[(size_t)(c0+ty+i)*R + (r0+tx)] = __float2bfloat16(tile[tx][ty+i]);
}

// ---------------- bf16 MFMA GEMM, 3-buffer depth-2 pipeline + XCD swizzle + T2 seg-swizzle ----
// (unchanged from round 16 — conflicts measured 0)
template<int MODE, int BN>
__global__ __launch_bounds__(256, 2)
void gemm_bt_kernel(const u16* __restrict__ A, const u16* __restrict__ BT,
                    const float* __restrict__ bias,
                    __hip_bfloat16* __restrict__ Cb,
                    int M, int N, int K, float cscale, int gx){
  __shared__ u16 As[3][128*32];
  __shared__ u16 Bs[3][BN*32];
  const int bid = blockIdx.x, nwg = gridDim.x;
  const int lin = (bid & 7)*(nwg >> 3) + (bid >> 3);
  const int m0 = (lin / gx)*128, n0 = (lin % gx)*BN;
  const int t = threadIdx.x;
  const int wid = t>>6, lane = t&63;
  const int wm = wid>>1, wn = wid&1;
  const int lr = lane&15, lg = lane>>4;
  const int lks = (lg ^ ((lr>>1)&3))*8;     // swizzled read chunk (u16 offset)
  const int srow = t>>2;
  const int sswz = ((t&3) ^ ((srow>>1)&3))*8; // pre-swizzled source chunk (u16 offset)
  const int wbase = wid*512;

  constexpr int NJ = BN/32;
  f32x4 acc[4][NJ] = {};
  const int NK = K/32;

  auto STAGE = [&](int s, int bi){
    const int kn = s*32;
    #pragma unroll
    for (int c=0;c<2;++c)
      load_lds16(A + (size_t)(m0 + c*64 + srow)*K + kn + sswz, &As[bi][c*2048 + wbase]);
    #pragma unroll
    for (int c=0;c<BN/64;++c)
      load_lds16(BT + (size_t)(n0 + c*64 + srow)*K + kn + sswz, &Bs[bi][c*2048 + wbase]);
  };

  STAGE(0,0);
  STAGE(1,1);
  if constexpr (BN==128) asm volatile("s_waitcnt vmcnt(4)" ::: "memory");
  else                   asm volatile("s_waitcnt vmcnt(3)" ::: "memory");
  __builtin_amdgcn_s_barrier();

  for (int kt=0; kt<NK; ++kt){
    const int cur = kt%3;
    if (kt+2 < NK) STAGE(kt+2, (kt+2)%3);
    bf16x8 af[4], bfr[NJ];
    #pragma unroll
    for (int f=0; f<4; ++f)
      af[f]  = *(const bf16x8*)&As[cur][(wm*64 + f*16 + lr)*32 + lks];
    #pragma unroll
    for (int j=0; j<NJ; ++j)
      bfr[j] = *(const bf16x8*)&Bs[cur][(wn*(BN/2) + j*16 + lr)*32 + lks];
    __builtin_amdgcn_s_setprio(1);
    #pragma unroll
    for (int i=0;i<4;++i)
      #pragma unroll
      for (int j=0;j<NJ;++j)
        acc[i][j] = __builtin_amdgcn_mfma_f32_16x16x32_bf16(af[i], bfr[j], acc[i][j], 0,0,0);
    __builtin_amdgcn_s_setprio(0);
    if (kt+2 < NK){
      if constexpr (BN==128) asm volatile("s_waitcnt vmcnt(4)" ::: "memory");
      else                   asm volatile("s_waitcnt vmcnt(3)" ::: "memory");
      __builtin_amdgcn_s_barrier();
    } else if (kt+1 < NK){
      asm volatile("s_waitcnt vmcnt(0)" ::: "memory");
      __builtin_amdgcn_s_barrier();
    }
  }

  const int r_in = lg*4;
  #pragma unroll
  for (int i=0;i<4;++i){
    #pragma unroll
    for (int j=0;j<NJ;++j){
      int col = n0 + wn*(BN/2) + j*16 + lr;
      float bv = bias ? bias[col] : 0.f;
      #pragma unroll
      for (int e=0;e<4;++e){
        int row = m0 + wm*64 + i*16 + r_in + e;
        float v = acc[i][j][e] + bv;
        if (MODE == 1){
          Cb[(size_t)row*N + col] = __float2bfloat16(v);
        } else { // MODE 5
          int b = row>>10, s = row&1023;
          int which = col>>10, c = col&1023, h = c>>6, d = c&63;
          size_t hm = (((size_t)b*16 + h)*1024 + s)*64 + d;
          if (which == 0){
            Cb[hm] = __float2bfloat16(v * cscale);
          } else if (which == 1){
            Cb[4194304u + hm] = __float2bfloat16(v);
          } else {
            Cb[8388608u + (((size_t)b*16 + h)*64 + d)*1024 + s] = __float2bfloat16(v);
          }
        }
      }
    }
  }
}

// ---------------- MFMA flash attention v5 (8 waves x 16q) ----------------
__global__ __launch_bounds__(512)
void attn_mfma_kernel(const u16* __restrict__ qb, const u16* __restrict__ kb,
                      const u16* __restrict__ vt, const int* __restrict__ mask,
                      __hip_bfloat16* __restrict__ out){
  __shared__ u16 Ks[2][64*72];
  __shared__ u16 Vs[2][64*72];
  __shared__ u16 Pl[8][16*72];
  __shared__ int s_allv;
  const int t = threadIdx.x;
  const int wid = t>>6, lane = t&63;
  const int lr = lane&15, lg = lane>>4, lk = lg*8;
  const int bid = blockIdx.x;
  const int xcd = bid & 7, slot = bid >> 3;
  const int bh = xcd*8 + (slot>>3);
  const int qx = slot & 7;
  const int b = bh>>4, h = bh&15;
  const int q0 = qx*128 + wid*16;
  const u16* qbase = qb + (size_t)bh*1024*64;
  const u16* kbase = kb + (size_t)bh*1024*64;
  const u16* vbase = vt + (size_t)bh*64*1024;
  const int* mrow = mask + b*SEQ;

  if (t==0) s_allv = 1;
  __syncthreads();
  if (mrow[t*2]==0 || mrow[t*2+1]==0) atomicAnd(&s_allv, 0);

  bf16x8 aq[2];
  aq[0] = *(const bf16x8*)(qbase + (size_t)(q0+lr)*64 + lk);
  aq[1] = *(const bf16x8*)(qbase + (size_t)(q0+lr)*64 + 32 + lk);

  f32x4 osum[4] = {};
  float m1 = -1e30f, l1 = 0.f;

  const int sr = t>>3, sg = (t&7)*8;
  {
    u32x4 kr = *(const u32x4*)(kbase + (size_t)sr*64 + sg);
    u32x4 vr = *(const u32x4*)(vbase + (size_t)sr*1024 + sg);
    *(u32x4*)&Ks[0][sr*72+sg] = kr;
    *(u32x4*)&Vs[0][sr*72+sg] = vr;
  }
  __syncthreads();
  const bool allv = (s_allv != 0);

  for (int kt=0; kt<SEQ/64; ++kt){
    const int k0 = kt*64;
    const int cur = kt&1;
    u32x4 kr, vr;
    const bool more = (kt+1 < SEQ/64);
    if (more){
      kr = *(const u32x4*)(kbase + (size_t)(k0+64+sr)*64 + sg);
      vr = *(const u32x4*)(vbase + (size_t)sr*1024 + (k0+64) + sg);
    }

    f32x4 sacc[4] = {};
    __builtin_amdgcn_s_setprio(1);
    #pragma unroll
    for (int k4=0;k4<4;++k4){
      #pragma unroll
      for (int dg=0;dg<2;++dg){
        bf16x8 kf = *(const bf16x8*)&Ks[cur][(k4*16+lr)*72 + dg*32 + lk];
        sacc[k4] = __builtin_amdgcn_mfma_f32_16x16x32_bf16(kf, aq[dg], sacc[k4],0,0,0);
      }
    }
    __builtin_amdgcn_s_setprio(0);
    if (!allv){
      unsigned long long bm = __ballot(mrow[k0 + lane] != 0);
      if (bm != ~0ull){
        #pragma unroll
        for (int k4=0;k4<4;++k4)
          #pragma unroll
          for (int e=0;e<4;++e)
            if (!((bm >> (k4*16 + lg*4 + e)) & 1)) sacc[k4][e] = -1e30f;
      }
    }

    float mx[4];
    #pragma unroll
    for (int k4=0;k4<4;++k4)
      mx[k4] = fmaxf(fmaxf(sacc[k4][0],sacc[k4][1]), fmaxf(sacc[k4][2],sacc[k4][3]));
    float tm = fmaxf(fmaxf(mx[0],mx[1]), fmaxf(mx[2],mx[3]));
    tm = fmaxf(tm, __shfl_xor(tm,16));
    tm = fmaxf(tm, __shfl_xor(tm,32));

    float mn = m1, c = 1.f;
    bool need = !__all(tm <= m1 + 8.f);
    if (need){
      mn = fmaxf(m1, tm);
      c  = fexp2(m1 - mn);
      m1 = mn;
    }
    float pp[4];
    #pragma unroll
    for (int k4=0;k4<4;++k4){
      #pragma unroll
      for (int e=0;e<4;++e) sacc[k4][e] = fexp2(sacc[k4][e]-mn);
      pp[k4] = (sacc[k4][0]+sacc[k4][1]) + (sacc[k4][2]+sacc[k4][3]);
    }
    float ps = (pp[0]+pp[1]) + (pp[2]+pp[3]);
    ps += __shfl_xor(ps,16);
    ps += __shfl_xor(ps,32);
    l1 = l1*c + ps;

    if (need){
      float ce[4];
      #pragma unroll
      for (int e=0;e<4;++e) ce[e] = __shfl(c, lg*4+e);
      #pragma unroll
      for (int dt=0;dt<4;++dt)
        #pragma unroll
        for (int e=0;e<4;++e) osum[dt][e] *= ce[e];
    }

    #pragma unroll
    for (int k4=0;k4<4;++k4){
      u32 lo = (u32)f2bf(sacc[k4][0]) | ((u32)f2bf(sacc[k4][1])<<16);
      u32 hi = (u32)f2bf(sacc[k4][2]) | ((u32)f2bf(sacc[k4][3])<<16);
      u32x2 pk; pk[0]=lo; pk[1]=hi;
      *(u32x2*)&Pl[wid][lr*72 + k4*16 + lg*4] = pk;
    }
    __builtin_amdgcn_s_setprio(1);
    #pragma unroll
    for (int dt=0;dt<4;++dt){
      #pragma unroll
      for (int kg=0;kg<2;++kg){
        bf16x8 pa = *(const bf16x8*)&Pl[wid][lr*72 + kg*32 + lk];
        bf16x8 vf = *(const bf16x8*)&Vs[cur][(dt*16+lr)*72 + kg*32 + lk];
        osum[dt] = __builtin_amdgcn_mfma_f32_16x16x32_bf16(pa, vf, osum[dt],0,0,0);
      }
    }
    __builtin_amdgcn_s_setprio(0);

    if (more){
      *(u32x4*)&Ks[cur^1][sr*72+sg] = kr;
      *(u32x4*)&Vs[cur^1][sr*72+sg] = vr;
    }
    __syncthreads();
  }
  float li[4];
  #pragma unroll
  for (int e=0;e<4;++e) li[e] = 1.f / __shfl(l1, lg*4+e);
  #pragma unroll
  for (int dt=0;dt<4;++dt){
    int d = dt*16 + lr;
    #pragma unroll
    for (int e=0;e<4;++e){
      int q = q0 + lg*4 + e;
      out[((size_t)b*1024 + q)*1024 + h*64 + d] = __float2bfloat16(osum[dt][e] * li[e]);
    }
  }
}

// ---------------- fused: t = relu(a) + res(*rscale); y = LN(t)*g+b ----------------
template<int RES_HM, int OUT_F32>
__global__ __launch_bounds__(256)
void ln_fused2_kernel(const u16* __restrict__ a, const u16* __restrict__ res,
                      const float* __restrict__ g, const float* __restrict__ be,
                      float rscale, float* __restrict__ outf, __hip_bfloat16* __restrict__ outb){
  int row = blockIdx.x, t = threadIdx.x;
  size_t rb = (size_t)row*D_MODEL;
  u32x2 av = *(const u32x2*)(a + rb + t*4);
  u32x2 rv;
  if (RES_HM){
    int b = row>>10, s = row&1023, h = t>>4, d = (t*4)&63;
    rv = *(const u32x2*)(res + (((size_t)(b*16+h)*1024 + s)*64 + d));
  } else {
    rv = *(const u32x2*)(res + rb + t*4);
  }
  float v0 = fmaxf(b2f((u16)(av[0]&0xffffu)),0.f) + b2f((u16)(rv[0]&0xffffu))*rscale;
  float v1 = fmaxf(b2f((u16)(av[0]>>16)),  0.f) + b2f((u16)(rv[0]>>16))*rscale;
  float v2 = fmaxf(b2f((u16)(av[1]&0xffffu)),0.f) + b2f((u16)(rv[1]&0xffffu))*rscale;
  float v3 = fmaxf(b2f((u16)(av[1]>>16)),  0.f) + b2f((u16)(rv[1]>>16))*rscale;
  float sum = v0+v1+v2+v3;
  float ss  = v0*v0+v1*v1+v2*v2+v3*v3;
  #pragma unroll
  for (int off=32; off; off>>=1){ sum += __shfl_xor(sum,off); ss += __shfl_xor(ss,off); }
  __shared__ float red[8];
  int wid = t>>6, lane = t&63;
  if (lane==0){ red[wid]=sum; red[4+wid]=ss; }
  __syncthreads();
  sum = red[0]+red[1]+red[2]+red[3];
  ss  = red[4]+red[5]+red[6]+red[7];
  float mu  = sum*(1.f/1024.f);
  float var = ss*(1.f/1024.f) - mu*mu;
  float rstd = rsqrtf(var + 1e-6f);
  float4 gv = *(const float4*)(g  + t*4);
  float4 bv = *(const float4*)(be + t*4);
  float y0=(v0-mu)*rstd*gv.x+bv.x;
  float y1=(v1-mu)*rstd*gv.y+bv.y;
  float y2=(v2-mu)*rstd*gv.z+bv.z;
  float y3=(v3-mu)*rstd*gv.w+bv.w;
  if (OUT_F32){
    *(float4*)(outf+rb+t*4) = make_float4(y0,y1,y2,y3);
  } else {
    outb[rb+t*4+0]=__float2bfloat16(y0);
    outb[rb+t*4+1]=__float2bfloat16(y1);
    outb[rb+t*4+2]=__float2bfloat16(y2);
    outb[rb+t*4+3]=__float2bfloat16(y3);
  }
}

extern "C" void kernel_launch(void* const* d_in, const int* in_sizes, int n_in,
                              void* d_out, int out_size, void* d_ws, size_t ws_size,
                              hipStream_t stream){
  const float* x    = (const float*)d_in[0];
  const int*   mask = (const int*)  d_in[1];
  const float* Wq   = (const float*)d_in[2];
  const float* Wk   = (const float*)d_in[3];
  const float* Wv   = (const float*)d_in[4];
  const float* Wo   = (const float*)d_in[5];
  const float* bo   = (const float*)d_in[6];
  const float* ln1g = (const float*)d_in[7];
  const float* ln1b = (const float*)d_in[8];
  const float* W1   = (const float*)d_in[9];
  const float* b1   = (const float*)d_in[10];
  const float* W2   = (const float*)d_in[11];
  const float* b2   = (const float*)d_in[12];
  const float* ln2g = (const float*)d_in[13];
  const float* ln2b = (const float*)d_in[14];

  char* ws = (char*)d_ws;
  const size_t MB = 1024*1024;
  __hip_bfloat16* WqT  = (__hip_bfloat16*)(ws + 0);
  __hip_bfloat16* WoT  = (__hip_bfloat16*)(ws + 6*MB);
  __hip_bfloat16* W1T  = (__hip_bfloat16*)(ws + 8*MB);
  __hip_bfloat16* W2T  = (__hip_bfloat16*)(ws + 12*MB);
  __hip_bfloat16* xb   = (__hip_bfloat16*)(ws + 16*MB);
  __hip_bfloat16* h1b  = (__hip_bfloat16*)(ws + 16*MB);
  __hip_bfloat16* ff1b = (__hip_bfloat16*)(ws + 24*MB);
  __hip_bfloat16* qb   = (__hip_bfloat16*)(ws + 40*MB);
  __hip_bfloat16* o_b  = (__hip_bfloat16*)(ws + 56*MB);
  __hip_bfloat16* f2b  = (__hip_bfloat16*)(ws + 56*MB);
  __hip_bfloat16* attn_o = (__hip_bfloat16*)(ws + 64*MB);

  const float qscale = 0.03125f * 1.44269504f;   // log2(e)/sqrt(D_MODEL)
  const float qunscale = 1.0f / qscale;

  // 1. prep
  cast_bf16_kernel<<<ROWS*D_MODEL/4/256, 256, 0, stream>>>(x, xb, ROWS*D_MODEL);
  transpose4_kernel<<<dim3(32,32,4), 256, 0, stream>>>(Wq, Wk, Wv, Wo, WqT);
  transpose_cast2_kernel<<<dim3(64,32,2), 256, 0, stream>>>(W1, W2, W1T, W2T);

  // 2. fused QKV projection: flat 768 blocks (gx=24, 3 blocks/CU), XCD row-panel swizzle
  gemm_bt_kernel<5,128><<<768, 256, 0, stream>>>((const u16*)xb, (const u16*)WqT, nullptr,
                                                 qb, ROWS, 3072, 1024, qscale, 24);

  // 3. MFMA flash attention (v5: 8 waves, 512 thr)
  attn_mfma_kernel<<<512, 512, 0, stream>>>(
      (const u16*)qb, (const u16*)(qb + 4194304u), (const u16*)(qb + 8388608u), mask, attn_o);

  // 4. O-proj: o_b = bf16(attn_o@Wo + bo); gx=16
  gemm_bt_kernel<1,64><<<512, 256, 0, stream>>>((const u16*)attn_o, (const u16*)WoT, bo,
                                                o_b, ROWS, 1024, 1024, 1.f, 16);

  // 5. ln1: h1b = bf16(LN(relu(o_b) + qb_hm/qscale))
  ln_fused2_kernel<1,0><<<ROWS, 256, 0, stream>>>((const u16*)o_b, (const u16*)qb,
                                                  ln1g, ln1b, qunscale, nullptr, h1b);

  // 6. FFN1: ff1b = bf16(h1b@W1 + b1); BN=64, gx=32 -> 1024 blocks = 4 blocks/CU (occupancy A/B)
  gemm_bt_kernel<1,64><<<1024, 256, 0, stream>>>((const u16*)h1b, (const u16*)W1T, b1,
                                                 ff1b, ROWS, 2048, 1024, 1.f, 32);

  // 7. FFN2: f2b = bf16(ff1b@W2 + b2); gx=16
  gemm_bt_kernel<1,64><<<512, 256, 0, stream>>>((const u16*)ff1b, (const u16*)W2T, b2,
                                                f2b, ROWS, 1024, 2048, 1.f, 16);

  // 8. ln2: y = LN(relu(f2b) + h1b)  (f32 out)
  ln_fused2_kernel<0,1><<<ROWS, 256, 0, stream>>>((const u16*)f2b, (const u16*)h1b,
                                                  ln2g, ln2b, 1.f, (float*)d_out, nullptr);
}

// Round 18
// 192.210 us; speedup vs baseline: 1.0170x; 1.0170x over previous
//
#include <hip/hip_runtime.h>
#include <hip/hip_bf16.h>

#define D_MODEL 1024
#define N_HEADS 16
#define D_HEAD  64
#define D_FF    2048
#define BATCH   4
#define SEQ     1024
#define ROWS    (BATCH*SEQ)   // 4096

typedef __bf16  bf16x8 __attribute__((ext_vector_type(8)));
typedef float   f32x4  __attribute__((ext_vector_type(4)));
typedef unsigned int u32x4 __attribute__((ext_vector_type(4)));
typedef unsigned int u32x2 __attribute__((ext_vector_type(2)));
typedef unsigned short u16;
typedef unsigned int u32;

__device__ inline u16 f2bf(float x){ __hip_bfloat16 b = __float2bfloat16(x); return *(u16*)&b; }
__device__ inline float b2f(u16 u){ u32 v = ((u32)u)<<16; return __builtin_bit_cast(float, v); }

#if __has_builtin(__builtin_amdgcn_exp2f)
__device__ inline float fexp2(float x){ return __builtin_amdgcn_exp2f(x); }
#else
__device__ inline float fexp2(float x){ return exp2f(x); }
#endif

// async global->LDS, 16B per lane. gsrc per-lane, ldst wave-uniform base (+lane*16 implicit).
__device__ inline void load_lds16(const u16* gsrc, u16* ldst){
  __builtin_amdgcn_global_load_lds((const __attribute__((address_space(1))) void*)gsrc,
                                   (__attribute__((address_space(3))) void*)ldst, 16, 0, 0);
}

// ---------------- prep: f32 -> bf16 cast ----------------
__global__ __launch_bounds__(256)
void cast_bf16_kernel(const float* __restrict__ src, __hip_bfloat16* __restrict__ dst, int n){
  int i = (blockIdx.x*blockDim.x + threadIdx.x)*4;
  if (i + 3 < n){
    float4 v = *(const float4*)(src + i);
    dst[i+0] = __float2bfloat16(v.x);
    dst[i+1] = __float2bfloat16(v.y);
    dst[i+2] = __float2bfloat16(v.z);
    dst[i+3] = __float2bfloat16(v.w);
  }
}

// ALL weight transposes in one launch. z=0..3: 1024x1024 squares (Wq,Wk,Wv,Wo -> WT+z*1Mi);
// z=4: W1 (1024x2048); z=5: W2 (2048x1024). Grid (64,32,6); out-of-range blocks exit.
__global__ __launch_bounds__(256)
void transpose_all_kernel(const float* __restrict__ s0, const float* __restrict__ s1,
                          const float* __restrict__ s2, const float* __restrict__ s3,
                          const float* __restrict__ W1, const float* __restrict__ W2,
                          __hip_bfloat16* __restrict__ WT,
                          __hip_bfloat16* __restrict__ W1T, __hip_bfloat16* __restrict__ W2T){
  __shared__ float tile[32][33];
  const int z = blockIdx.z;
  const float* src; __hip_bfloat16* dst; int R, C, c0, r0;
  if (z < 4){
    if (blockIdx.x >= 32) return;
    src = (z==0)?s0:(z==1)?s1:(z==2)?s2:s3;
    dst = WT + (size_t)z*1024*1024;
    R = 1024; C = 1024; c0 = blockIdx.x*32; r0 = blockIdx.y*32;
  } else if (z == 4){
    src = W1; dst = W1T; R = 1024; C = 2048;
    c0 = blockIdx.x*32; r0 = blockIdx.y*32;
  } else {
    src = W2; dst = W2T; R = 2048; C = 1024;
    c0 = blockIdx.y*32; r0 = blockIdx.x*32;
  }
  int tx = threadIdx.x & 31, ty = threadIdx.x >> 5;
  #pragma unroll
  for (int i=0;i<32;i+=8)
    tile[ty+i][tx] = src[(size_t)(r0+ty+i)*C + (c0+tx)];
  __syncthreads();
  #pragma unroll
  for (int i=0;i<32;i+=8)
    dst[(size_t)(c0+ty+i)*R + (r0+tx)] = __float2bfloat16(tile[tx][ty+i]);
}

// ---------------- bf16 MFMA GEMM, 3-buffer depth-2 pipeline + XCD swizzle + T2 seg-swizzle ----
// (round-16 structure — bank conflicts measured 0)
template<int MODE, int BN>
__global__ __launch_bounds__(256, 2)
void gemm_bt_kernel(const u16* __restrict__ A, const u16* __restrict__ BT,
                    const float* __restrict__ bias,
                    __hip_bfloat16* __restrict__ Cb,
                    int M, int N, int K, float cscale, int gx){
  __shared__ u16 As[3][128*32];
  __shared__ u16 Bs[3][BN*32];
  const int bid = blockIdx.x, nwg = gridDim.x;
  const int lin = (bid & 7)*(nwg >> 3) + (bid >> 3);
  const int m0 = (lin / gx)*128, n0 = (lin % gx)*BN;
  const int t = threadIdx.x;
  const int wid = t>>6, lane = t&63;
  const int wm = wid>>1, wn = wid&1;
  const int lr = lane&15, lg = lane>>4;
  const int lks = (lg ^ ((lr>>1)&3))*8;       // swizzled read chunk (u16 offset)
  const int srow = t>>2;
  const int sswz = ((t&3) ^ ((srow>>1)&3))*8; // pre-swizzled source chunk (u16 offset)
  const int wbase = wid*512;

  constexpr int NJ = BN/32;
  f32x4 acc[4][NJ] = {};
  const int NK = K/32;

  auto STAGE = [&](int s, int bi){
    const int kn = s*32;
    #pragma unroll
    for (int c=0;c<2;++c)
      load_lds16(A + (size_t)(m0 + c*64 + srow)*K + kn + sswz, &As[bi][c*2048 + wbase]);
    #pragma unroll
    for (int c=0;c<BN/64;++c)
      load_lds16(BT + (size_t)(n0 + c*64 + srow)*K + kn + sswz, &Bs[bi][c*2048 + wbase]);
  };

  STAGE(0,0);
  STAGE(1,1);
  if constexpr (BN==128) asm volatile("s_waitcnt vmcnt(4)" ::: "memory");
  else                   asm volatile("s_waitcnt vmcnt(3)" ::: "memory");
  __builtin_amdgcn_s_barrier();

  for (int kt=0; kt<NK; ++kt){
    const int cur = kt%3;
    if (kt+2 < NK) STAGE(kt+2, (kt+2)%3);
    bf16x8 af[4], bfr[NJ];
    #pragma unroll
    for (int f=0; f<4; ++f)
      af[f]  = *(const bf16x8*)&As[cur][(wm*64 + f*16 + lr)*32 + lks];
    #pragma unroll
    for (int j=0; j<NJ; ++j)
      bfr[j] = *(const bf16x8*)&Bs[cur][(wn*(BN/2) + j*16 + lr)*32 + lks];
    __builtin_amdgcn_s_setprio(1);
    #pragma unroll
    for (int i=0;i<4;++i)
      #pragma unroll
      for (int j=0;j<NJ;++j)
        acc[i][j] = __builtin_amdgcn_mfma_f32_16x16x32_bf16(af[i], bfr[j], acc[i][j], 0,0,0);
    __builtin_amdgcn_s_setprio(0);
    if (kt+2 < NK){
      if constexpr (BN==128) asm volatile("s_waitcnt vmcnt(4)" ::: "memory");
      else                   asm volatile("s_waitcnt vmcnt(3)" ::: "memory");
      __builtin_amdgcn_s_barrier();
    } else if (kt+1 < NK){
      asm volatile("s_waitcnt vmcnt(0)" ::: "memory");
      __builtin_amdgcn_s_barrier();
    }
  }

  const int r_in = lg*4;
  #pragma unroll
  for (int i=0;i<4;++i){
    #pragma unroll
    for (int j=0;j<NJ;++j){
      int col = n0 + wn*(BN/2) + j*16 + lr;
      float bv = bias ? bias[col] : 0.f;
      #pragma unroll
      for (int e=0;e<4;++e){
        int row = m0 + wm*64 + i*16 + r_in + e;
        float v = acc[i][j][e] + bv;
        if (MODE == 1){
          Cb[(size_t)row*N + col] = __float2bfloat16(v);
        } else { // MODE 5
          int b = row>>10, s = row&1023;
          int which = col>>10, c = col&1023, h = c>>6, d = c&63;
          size_t hm = (((size_t)b*16 + h)*1024 + s)*64 + d;
          if (which == 0){
            Cb[hm] = __float2bfloat16(v * cscale);
          } else if (which == 1){
            Cb[4194304u + hm] = __float2bfloat16(v);
          } else {
            Cb[8388608u + (((size_t)b*16 + h)*64 + d)*1024 + s] = __float2bfloat16(v);
          }
        }
      }
    }
  }
}

// ---------------- MFMA flash attention v5 (8 waves x 16q) ----------------
__global__ __launch_bounds__(512)
void attn_mfma_kernel(const u16* __restrict__ qb, const u16* __restrict__ kb,
                      const u16* __restrict__ vt, const int* __restrict__ mask,
                      __hip_bfloat16* __restrict__ out){
  __shared__ u16 Ks[2][64*72];
  __shared__ u16 Vs[2][64*72];
  __shared__ u16 Pl[8][16*72];
  __shared__ int s_allv;
  const int t = threadIdx.x;
  const int wid = t>>6, lane = t&63;
  const int lr = lane&15, lg = lane>>4, lk = lg*8;
  const int bid = blockIdx.x;
  const int xcd = bid & 7, slot = bid >> 3;
  const int bh = xcd*8 + (slot>>3);
  const int qx = slot & 7;
  const int b = bh>>4, h = bh&15;
  const int q0 = qx*128 + wid*16;
  const u16* qbase = qb + (size_t)bh*1024*64;
  const u16* kbase = kb + (size_t)bh*1024*64;
  const u16* vbase = vt + (size_t)bh*64*1024;
  const int* mrow = mask + b*SEQ;

  if (t==0) s_allv = 1;
  __syncthreads();
  if (mrow[t*2]==0 || mrow[t*2+1]==0) atomicAnd(&s_allv, 0);

  bf16x8 aq[2];
  aq[0] = *(const bf16x8*)(qbase + (size_t)(q0+lr)*64 + lk);
  aq[1] = *(const bf16x8*)(qbase + (size_t)(q0+lr)*64 + 32 + lk);

  f32x4 osum[4] = {};
  float m1 = -1e30f, l1 = 0.f;

  const int sr = t>>3, sg = (t&7)*8;
  {
    u32x4 kr = *(const u32x4*)(kbase + (size_t)sr*64 + sg);
    u32x4 vr = *(const u32x4*)(vbase + (size_t)sr*1024 + sg);
    *(u32x4*)&Ks[0][sr*72+sg] = kr;
    *(u32x4*)&Vs[0][sr*72+sg] = vr;
  }
  __syncthreads();
  const bool allv = (s_allv != 0);

  for (int kt=0; kt<SEQ/64; ++kt){
    const int k0 = kt*64;
    const int cur = kt&1;
    u32x4 kr, vr;
    const bool more = (kt+1 < SEQ/64);
    if (more){
      kr = *(const u32x4*)(kbase + (size_t)(k0+64+sr)*64 + sg);
      vr = *(const u32x4*)(vbase + (size_t)sr*1024 + (k0+64) + sg);
    }

    f32x4 sacc[4] = {};
    __builtin_amdgcn_s_setprio(1);
    #pragma unroll
    for (int k4=0;k4<4;++k4){
      #pragma unroll
      for (int dg=0;dg<2;++dg){
        bf16x8 kf = *(const bf16x8*)&Ks[cur][(k4*16+lr)*72 + dg*32 + lk];
        sacc[k4] = __builtin_amdgcn_mfma_f32_16x16x32_bf16(kf, aq[dg], sacc[k4],0,0,0);
      }
    }
    __builtin_amdgcn_s_setprio(0);
    if (!allv){
      unsigned long long bm = __ballot(mrow[k0 + lane] != 0);
      if (bm != ~0ull){
        #pragma unroll
        for (int k4=0;k4<4;++k4)
          #pragma unroll
          for (int e=0;e<4;++e)
            if (!((bm >> (k4*16 + lg*4 + e)) & 1)) sacc[k4][e] = -1e30f;
      }
    }

    float mx[4];
    #pragma unroll
    for (int k4=0;k4<4;++k4)
      mx[k4] = fmaxf(fmaxf(sacc[k4][0],sacc[k4][1]), fmaxf(sacc[k4][2],sacc[k4][3]));
    float tm = fmaxf(fmaxf(mx[0],mx[1]), fmaxf(mx[2],mx[3]));
    tm = fmaxf(tm, __shfl_xor(tm,16));
    tm = fmaxf(tm, __shfl_xor(tm,32));

    float mn = m1, c = 1.f;
    bool need = !__all(tm <= m1 + 8.f);
    if (need){
      mn = fmaxf(m1, tm);
      c  = fexp2(m1 - mn);
      m1 = mn;
    }
    float pp[4];
    #pragma unroll
    for (int k4=0;k4<4;++k4){
      #pragma unroll
      for (int e=0;e<4;++e) sacc[k4][e] = fexp2(sacc[k4][e]-mn);
      pp[k4] = (sacc[k4][0]+sacc[k4][1]) + (sacc[k4][2]+sacc[k4][3]);
    }
    float ps = (pp[0]+pp[1]) + (pp[2]+pp[3]);
    ps += __shfl_xor(ps,16);
    ps += __shfl_xor(ps,32);
    l1 = l1*c + ps;

    if (need){
      float ce[4];
      #pragma unroll
      for (int e=0;e<4;++e) ce[e] = __shfl(c, lg*4+e);
      #pragma unroll
      for (int dt=0;dt<4;++dt)
        #pragma unroll
        for (int e=0;e<4;++e) osum[dt][e] *= ce[e];
    }

    #pragma unroll
    for (int k4=0;k4<4;++k4){
      u32 lo = (u32)f2bf(sacc[k4][0]) | ((u32)f2bf(sacc[k4][1])<<16);
      u32 hi = (u32)f2bf(sacc[k4][2]) | ((u32)f2bf(sacc[k4][3])<<16);
      u32x2 pk; pk[0]=lo; pk[1]=hi;
      *(u32x2*)&Pl[wid][lr*72 + k4*16 + lg*4] = pk;
    }
    __builtin_amdgcn_s_setprio(1);
    #pragma unroll
    for (int dt=0;dt<4;++dt){
      #pragma unroll
      for (int kg=0;kg<2;++kg){
        bf16x8 pa = *(const bf16x8*)&Pl[wid][lr*72 + kg*32 + lk];
        bf16x8 vf = *(const bf16x8*)&Vs[cur][(dt*16+lr)*72 + kg*32 + lk];
        osum[dt] = __builtin_amdgcn_mfma_f32_16x16x32_bf16(pa, vf, osum[dt],0,0,0);
      }
    }
    __builtin_amdgcn_s_setprio(0);

    if (more){
      *(u32x4*)&Ks[cur^1][sr*72+sg] = kr;
      *(u32x4*)&Vs[cur^1][sr*72+sg] = vr;
    }
    __syncthreads();
  }
  float li[4];
  #pragma unroll
  for (int e=0;e<4;++e) li[e] = 1.f / __shfl(l1, lg*4+e);
  #pragma unroll
  for (int dt=0;dt<4;++dt){
    int d = dt*16 + lr;
    #pragma unroll
    for (int e=0;e<4;++e){
      int q = q0 + lg*4 + e;
      out[((size_t)b*1024 + q)*1024 + h*64 + d] = __float2bfloat16(osum[dt][e] * li[e]);
    }
  }
}

// ---------------- fused: t = relu(a) + res(*rscale); y = LN(t)*g+b ----------------
template<int RES_HM, int OUT_F32>
__global__ __launch_bounds__(256)
void ln_fused2_kernel(const u16* __restrict__ a, const u16* __restrict__ res,
                      const float* __restrict__ g, const float* __restrict__ be,
                      float rscale, float* __restrict__ outf, __hip_bfloat16* __restrict__ outb){
  int row = blockIdx.x, t = threadIdx.x;
  size_t rb = (size_t)row*D_MODEL;
  u32x2 av = *(const u32x2*)(a + rb + t*4);
  u32x2 rv;
  if (RES_HM){
    int b = row>>10, s = row&1023, h = t>>4, d = (t*4)&63;
    rv = *(const u32x2*)(res + (((size_t)(b*16+h)*1024 + s)*64 + d));
  } else {
    rv = *(const u32x2*)(res + rb + t*4);
  }
  float v0 = fmaxf(b2f((u16)(av[0]&0xffffu)),0.f) + b2f((u16)(rv[0]&0xffffu))*rscale;
  float v1 = fmaxf(b2f((u16)(av[0]>>16)),  0.f) + b2f((u16)(rv[0]>>16))*rscale;
  float v2 = fmaxf(b2f((u16)(av[1]&0xffffu)),0.f) + b2f((u16)(rv[1]&0xffffu))*rscale;
  float v3 = fmaxf(b2f((u16)(av[1]>>16)),  0.f) + b2f((u16)(rv[1]>>16))*rscale;
  float sum = v0+v1+v2+v3;
  float ss  = v0*v0+v1*v1+v2*v2+v3*v3;
  #pragma unroll
  for (int off=32; off; off>>=1){ sum += __shfl_xor(sum,off); ss += __shfl_xor(ss,off); }
  __shared__ float red[8];
  int wid = t>>6, lane = t&63;
  if (lane==0){ red[wid]=sum; red[4+wid]=ss; }
  __syncthreads();
  sum = red[0]+red[1]+red[2]+red[3];
  ss  = red[4]+red[5]+red[6]+red[7];
  float mu  = sum*(1.f/1024.f);
  float var = ss*(1.f/1024.f) - mu*mu;
  float rstd = rsqrtf(var + 1e-6f);
  float4 gv = *(const float4*)(g  + t*4);
  float4 bv = *(const float4*)(be + t*4);
  float y0=(v0-mu)*rstd*gv.x+bv.x;
  float y1=(v1-mu)*rstd*gv.y+bv.y;
  float y2=(v2-mu)*rstd*gv.z+bv.z;
  float y3=(v3-mu)*rstd*gv.w+bv.w;
  if (OUT_F32){
    *(float4*)(outf+rb+t*4) = make_float4(y0,y1,y2,y3);
  } else {
    outb[rb+t*4+0]=__float2bfloat16(y0);
    outb[rb+t*4+1]=__float2bfloat16(y1);
    outb[rb+t*4+2]=__float2bfloat16(y2);
    outb[rb+t*4+3]=__float2bfloat16(y3);
  }
}

extern "C" void kernel_launch(void* const* d_in, const int* in_sizes, int n_in,
                              void* d_out, int out_size, void* d_ws, size_t ws_size,
                              hipStream_t stream){
  const float* x    = (const float*)d_in[0];
  const int*   mask = (const int*)  d_in[1];
  const float* Wq   = (const float*)d_in[2];
  const float* Wk   = (const float*)d_in[3];
  const float* Wv   = (const float*)d_in[4];
  const float* Wo   = (const float*)d_in[5];
  const float* bo   = (const float*)d_in[6];
  const float* ln1g = (const float*)d_in[7];
  const float* ln1b = (const float*)d_in[8];
  const float* W1   = (const float*)d_in[9];
  const float* b1   = (const float*)d_in[10];
  const float* W2   = (const float*)d_in[11];
  const float* b2   = (const float*)d_in[12];
  const float* ln2g = (const float*)d_in[13];
  const float* ln2b = (const float*)d_in[14];

  char* ws = (char*)d_ws;
  const size_t MB = 1024*1024;
  __hip_bfloat16* WqT  = (__hip_bfloat16*)(ws + 0);
  __hip_bfloat16* WoT  = (__hip_bfloat16*)(ws + 6*MB);
  __hip_bfloat16* W1T  = (__hip_bfloat16*)(ws + 8*MB);
  __hip_bfloat16* W2T  = (__hip_bfloat16*)(ws + 12*MB);
  __hip_bfloat16* xb   = (__hip_bfloat16*)(ws + 16*MB);
  __hip_bfloat16* h1b  = (__hip_bfloat16*)(ws + 16*MB);
  __hip_bfloat16* ff1b = (__hip_bfloat16*)(ws + 24*MB);
  __hip_bfloat16* qb   = (__hip_bfloat16*)(ws + 40*MB);
  __hip_bfloat16* o_b  = (__hip_bfloat16*)(ws + 56*MB);
  __hip_bfloat16* f2b  = (__hip_bfloat16*)(ws + 56*MB);
  __hip_bfloat16* attn_o = (__hip_bfloat16*)(ws + 64*MB);

  const float qscale = 0.03125f * 1.44269504f;   // log2(e)/sqrt(D_MODEL)
  const float qunscale = 1.0f / qscale;

  // 1. prep (2 launches)
  cast_bf16_kernel<<<ROWS*D_MODEL/4/256, 256, 0, stream>>>(x, xb, ROWS*D_MODEL);
  transpose_all_kernel<<<dim3(64,32,6), 256, 0, stream>>>(Wq, Wk, Wv, Wo, W1, W2,
                                                          WqT, W1T, W2T);

  // 2. fused QKV projection: flat 768 blocks (gx=24, 3 blocks/CU), XCD row-panel swizzle
  gemm_bt_kernel<5,128><<<768, 256, 0, stream>>>((const u16*)xb, (const u16*)WqT, nullptr,
                                                 qb, ROWS, 3072, 1024, qscale, 24);

  // 3. MFMA flash attention (v5: 8 waves, 512 thr)
  attn_mfma_kernel<<<512, 512, 0, stream>>>(
      (const u16*)qb, (const u16*)(qb + 4194304u), (const u16*)(qb + 8388608u), mask, attn_o);

  // 4. O-proj: o_b = bf16(attn_o@Wo + bo); gx=16
  gemm_bt_kernel<1,64><<<512, 256, 0, stream>>>((const u16*)attn_o, (const u16*)WoT, bo,
                                                o_b, ROWS, 1024, 1024, 1.f, 16);

  // 5. ln1: h1b = bf16(LN(relu(o_b) + qb_hm/qscale))
  ln_fused2_kernel<1,0><<<ROWS, 256, 0, stream>>>((const u16*)o_b, (const u16*)qb,
                                                  ln1g, ln1b, qunscale, nullptr, h1b);

  // 6. FFN1: ff1b = bf16(h1b@W1 + b1); BN=128, gx=16 (best-measured config)
  gemm_bt_kernel<1,128><<<512, 256, 0, stream>>>((const u16*)h1b, (const u16*)W1T, b1,
                                                 ff1b, ROWS, 2048, 1024, 1.f, 16);

  // 7. FFN2: f2b = bf16(ff1b@W2 + b2); gx=16
  gemm_bt_kernel<1,64><<<512, 256, 0, stream>>>((const u16*)ff1b, (const u16*)W2T, b2,
                                                f2b, ROWS, 1024, 2048, 1.f, 16);

  // 8. ln2: y = LN(relu(f2b) + h1b)  (f32 out)
  ln_fused2_kernel<0,1><<<ROWS, 256, 0, stream>>>((const u16*)f2b, (const u16*)h1b,
                                                  ln2g, ln2b, 1.f, (float*)d_out, nullptr);
}